// Round 1
// baseline (3259.896 us; speedup 1.0000x reference)
//
#include <hip/hip_runtime.h>

#define NNODES 50000
#define NEDGES 600000
#define HID 128
#define NLAYERS 3
#define NEG 0.01f

// Scatter kernel: 32 lanes per edge, 4 features per lane.
// Computes msg = relu(h[src] + ea@Wl + bl) and atomically adds into agg[dst].
// agg must be pre-initialized to h (so it ends as h + sum(msg)).
__global__ __launch_bounds__(256) void scatter_k(
    const float* __restrict__ h,
    const int* __restrict__ ei,     // [2, E] (src row, then dst row)
    const float* __restrict__ ea,   // [E, 2]
    const float* __restrict__ Wl,   // [2, HID] this layer
    const float* __restrict__ bl,   // [HID] this layer
    float* __restrict__ agg)        // [N, HID]
{
    const int tid = blockIdx.x * blockDim.x + threadIdx.x;
    const int f0 = (tid & 31) << 2;                    // feature offset 0..124
    const int estride = (gridDim.x * blockDim.x) >> 5; // edges per sweep
    const float4 w0 = *(const float4*)(Wl + f0);
    const float4 w1 = *(const float4*)(Wl + HID + f0);
    const float4 bb = *(const float4*)(bl + f0);
    for (int e = tid >> 5; e < NEDGES; e += estride) {
        const int s = ei[e];
        const int d = ei[NEDGES + e];
        const float a0 = ea[2 * e];
        const float a1 = ea[2 * e + 1];
        const float4 hv = *(const float4*)(h + (size_t)s * HID + f0);
        const float m0 = fmaxf(fmaf(a0, w0.x, fmaf(a1, w1.x, bb.x)) + hv.x, 0.f);
        const float m1 = fmaxf(fmaf(a0, w0.y, fmaf(a1, w1.y, bb.y)) + hv.y, 0.f);
        const float m2 = fmaxf(fmaf(a0, w0.z, fmaf(a1, w1.z, bb.z)) + hv.z, 0.f);
        const float m3 = fmaxf(fmaf(a0, w0.w, fmaf(a1, w1.w, bb.w)) + hv.w, 0.f);
        float* ap = agg + (size_t)d * HID + f0;
        atomicAdd(ap + 0, m0);
        atomicAdd(ap + 1, m1);
        atomicAdd(ap + 2, m2);
        atomicAdd(ap + 3, m3);
    }
}

// Register-tiled skinny GEMM: out = leakyrelu(v @ W + bias).
// Block = 256 threads covers 64 rows x 128 cols; thread = 8 rows x 4 cols.
__global__ __launch_bounds__(256) void gemm_k(
    const float* __restrict__ v,     // [N, HID] (agg = h + sum msg)
    const float* __restrict__ W,     // [HID, HID]
    const float* __restrict__ bias,  // [HID]
    float* __restrict__ out)         // [N, HID]
{
    const int tid = threadIdx.x;
    const int row0 = blockIdx.x * 64 + ((tid >> 5) << 3);
    const int f0 = (tid & 31) << 2;
    const float4 bb = *(const float4*)(bias + f0);
    float acc[8][4];
#pragma unroll
    for (int i = 0; i < 8; ++i) {
        acc[i][0] = bb.x; acc[i][1] = bb.y; acc[i][2] = bb.z; acc[i][3] = bb.w;
    }
    for (int k = 0; k < HID; k += 4) {
        const float4 wr0 = *(const float4*)(W + (size_t)(k + 0) * HID + f0);
        const float4 wr1 = *(const float4*)(W + (size_t)(k + 1) * HID + f0);
        const float4 wr2 = *(const float4*)(W + (size_t)(k + 2) * HID + f0);
        const float4 wr3 = *(const float4*)(W + (size_t)(k + 3) * HID + f0);
#pragma unroll
        for (int i = 0; i < 8; ++i) {
            const int r = row0 + i;
            if (r < NNODES) {
                const float4 vv = *(const float4*)(v + (size_t)r * HID + k);
                acc[i][0] = fmaf(vv.x, wr0.x, fmaf(vv.y, wr1.x, fmaf(vv.z, wr2.x, fmaf(vv.w, wr3.x, acc[i][0]))));
                acc[i][1] = fmaf(vv.x, wr0.y, fmaf(vv.y, wr1.y, fmaf(vv.z, wr2.y, fmaf(vv.w, wr3.y, acc[i][1]))));
                acc[i][2] = fmaf(vv.x, wr0.z, fmaf(vv.y, wr1.z, fmaf(vv.z, wr2.z, fmaf(vv.w, wr3.z, acc[i][2]))));
                acc[i][3] = fmaf(vv.x, wr0.w, fmaf(vv.y, wr1.w, fmaf(vv.z, wr2.w, fmaf(vv.w, wr3.w, acc[i][3]))));
            }
        }
    }
#pragma unroll
    for (int i = 0; i < 8; ++i) {
        const int r = row0 + i;
        if (r < NNODES) {
            float4 o;
            o.x = acc[i][0] >= 0.f ? acc[i][0] : NEG * acc[i][0];
            o.y = acc[i][1] >= 0.f ? acc[i][1] : NEG * acc[i][1];
            o.z = acc[i][2] >= 0.f ? acc[i][2] : NEG * acc[i][2];
            o.w = acc[i][3] >= 0.f ? acc[i][3] : NEG * acc[i][3];
            *(float4*)(out + (size_t)r * HID + f0) = o;
        }
    }
}

extern "C" void kernel_launch(void* const* d_in, const int* in_sizes, int n_in,
                              void* d_out, int out_size, void* d_ws, size_t ws_size,
                              hipStream_t stream) {
    const float* x  = (const float*)d_in[0];
    const int*   ei = (const int*)d_in[1];
    const float* ea = (const float*)d_in[2];
    const float* Wl = (const float*)d_in[3];
    const float* bl = (const float*)d_in[4];
    const float* W  = (const float*)d_in[5];
    const float* b  = (const float*)d_in[6];

    float* h   = (float*)d_out;  // node features live in d_out across layers
    float* agg = (float*)d_ws;   // [N, HID] scratch

    const size_t hbytes = (size_t)NNODES * HID * sizeof(float);

    for (int l = 0; l < NLAYERS; ++l) {
        const float* hcur = (l == 0) ? x : h;
        // agg = h  (atomics then accumulate h + sum(msg))
        hipMemcpyAsync(agg, hcur, hbytes, hipMemcpyDeviceToDevice, stream);
        scatter_k<<<2048, 256, 0, stream>>>(
            hcur, ei, ea, Wl + (size_t)l * 2 * HID, bl + (size_t)l * HID, agg);
        gemm_k<<<(NNODES + 63) / 64, 256, 0, stream>>>(
            agg, W + (size_t)l * HID * HID, b + (size_t)l * HID, h);
    }
}

// Round 2
// 649.702 us; speedup vs baseline: 5.0175x; 5.0175x over previous
//
#include <hip/hip_runtime.h>

#define NNODES 50000
#define NEDGES 600000
#define HID 128
#define NLAYERS 3
#define NEG 0.01f

// ---------- CSR build (once per call; edge list is layer-invariant) ----------

// deg[d]++ for every edge's destination. `deg` aliases the `off` array (zeroed first).
__global__ __launch_bounds__(256) void hist_k(const int* __restrict__ ei,
                                              int* __restrict__ deg) {
    const int e = blockIdx.x * blockDim.x + threadIdx.x;
    if (e < NEDGES) atomicAdd(&deg[ei[NEDGES + e]], 1);
}

// Single-block exclusive prefix scan of off[0..NNODES) in place; off[NNODES] = E.
// Also writes a second cursor copy for the fill kernel.
__global__ __launch_bounds__(1024) void scan_k(int* __restrict__ off,
                                               int* __restrict__ cur) {
    __shared__ int s[1024];
    const int t = threadIdx.x;
    int carry = 0;
    for (int base = 0; base < NNODES; base += 1024) {
        const int i = base + t;
        const int v = (i < NNODES) ? off[i] : 0;
        s[t] = v;
        __syncthreads();
        for (int d = 1; d < 1024; d <<= 1) {
            const int add = (t >= d) ? s[t - d] : 0;
            __syncthreads();
            s[t] += add;
            __syncthreads();
        }
        if (i < NNODES) {
            const int excl = carry + s[t] - v;
            off[i] = excl;
            cur[i] = excl;
        }
        const int total = s[1023];
        __syncthreads();
        carry += total;
    }
    if (t == 0) off[NNODES] = carry;
}

// perm[slot] = edge id, slots grouped by destination node.
__global__ __launch_bounds__(256) void fill_k(const int* __restrict__ ei,
                                              int* __restrict__ cur,
                                              int* __restrict__ perm) {
    const int e = blockIdx.x * blockDim.x + threadIdx.x;
    if (e < NEDGES) {
        const int d = ei[NEDGES + e];
        const int p = atomicAdd(&cur[d], 1);
        perm[p] = e;
    }
}

// ---------- Per-layer aggregation: one wave per node, zero float atomics ----------
// agg[n] = h[n] + sum over incoming edges of relu(h[src] + ea@Wl + bl)
__global__ __launch_bounds__(256) void agg_k(
    const float* __restrict__ h,
    const int* __restrict__ ei,
    const float* __restrict__ ea,
    const float* __restrict__ Wl,   // [2, HID]
    const float* __restrict__ bl,   // [HID]
    const int* __restrict__ off,
    const int* __restrict__ perm,
    float* __restrict__ agg)
{
    const int node = blockIdx.x * 4 + (threadIdx.x >> 6);
    if (node >= NNODES) return;
    const int lane = threadIdx.x & 63;
    const int f0 = lane << 1;
    const float2 w0 = *(const float2*)(Wl + f0);
    const float2 w1 = *(const float2*)(Wl + HID + f0);
    const float2 bb = *(const float2*)(bl + f0);
    float2 acc = *(const float2*)(h + (size_t)node * HID + f0);  // (1+eps)*h, eps=0
    const int e0 = off[node], e1 = off[node + 1];
    for (int idx = e0; idx < e1; ++idx) {
        const int e = perm[idx];
        const int s = ei[e];
        const float a0 = ea[2 * e];
        const float a1 = ea[2 * e + 1];
        const float2 hv = *(const float2*)(h + (size_t)s * HID + f0);
        const float p0 = fmaf(a0, w0.x, fmaf(a1, w1.x, bb.x));
        const float p1 = fmaf(a0, w0.y, fmaf(a1, w1.y, bb.y));
        acc.x += fmaxf(hv.x + p0, 0.f);
        acc.y += fmaxf(hv.y + p1, 0.f);
    }
    *(float2*)(agg + (size_t)node * HID + f0) = acc;
}

// ---------- Skinny GEMM: out = leakyrelu(v @ W + bias) ----------
__global__ __launch_bounds__(256) void gemm_k(
    const float* __restrict__ v,     // [N, HID]
    const float* __restrict__ W,     // [HID, HID]
    const float* __restrict__ bias,  // [HID]
    float* __restrict__ out)         // [N, HID]
{
    const int tid = threadIdx.x;
    const int row0 = blockIdx.x * 64 + ((tid >> 5) << 3);
    const int f0 = (tid & 31) << 2;
    const float4 bb = *(const float4*)(bias + f0);
    float acc[8][4];
#pragma unroll
    for (int i = 0; i < 8; ++i) {
        acc[i][0] = bb.x; acc[i][1] = bb.y; acc[i][2] = bb.z; acc[i][3] = bb.w;
    }
    for (int k = 0; k < HID; k += 4) {
        const float4 wr0 = *(const float4*)(W + (size_t)(k + 0) * HID + f0);
        const float4 wr1 = *(const float4*)(W + (size_t)(k + 1) * HID + f0);
        const float4 wr2 = *(const float4*)(W + (size_t)(k + 2) * HID + f0);
        const float4 wr3 = *(const float4*)(W + (size_t)(k + 3) * HID + f0);
#pragma unroll
        for (int i = 0; i < 8; ++i) {
            const int r = row0 + i;
            if (r < NNODES) {
                const float4 vv = *(const float4*)(v + (size_t)r * HID + k);
                acc[i][0] = fmaf(vv.x, wr0.x, fmaf(vv.y, wr1.x, fmaf(vv.z, wr2.x, fmaf(vv.w, wr3.x, acc[i][0]))));
                acc[i][1] = fmaf(vv.x, wr0.y, fmaf(vv.y, wr1.y, fmaf(vv.z, wr2.y, fmaf(vv.w, wr3.y, acc[i][1]))));
                acc[i][2] = fmaf(vv.x, wr0.z, fmaf(vv.y, wr1.z, fmaf(vv.z, wr2.z, fmaf(vv.w, wr3.z, acc[i][2]))));
                acc[i][3] = fmaf(vv.x, wr0.w, fmaf(vv.y, wr1.w, fmaf(vv.z, wr2.w, fmaf(vv.w, wr3.w, acc[i][3]))));
            }
        }
    }
#pragma unroll
    for (int i = 0; i < 8; ++i) {
        const int r = row0 + i;
        if (r < NNODES) {
            float4 o;
            o.x = acc[i][0] >= 0.f ? acc[i][0] : NEG * acc[i][0];
            o.y = acc[i][1] >= 0.f ? acc[i][1] : NEG * acc[i][1];
            o.z = acc[i][2] >= 0.f ? acc[i][2] : NEG * acc[i][2];
            o.w = acc[i][3] >= 0.f ? acc[i][3] : NEG * acc[i][3];
            *(float4*)(out + (size_t)r * HID + f0) = o;
        }
    }
}

extern "C" void kernel_launch(void* const* d_in, const int* in_sizes, int n_in,
                              void* d_out, int out_size, void* d_ws, size_t ws_size,
                              hipStream_t stream) {
    const float* x  = (const float*)d_in[0];
    const int*   ei = (const int*)d_in[1];
    const float* ea = (const float*)d_in[2];
    const float* Wl = (const float*)d_in[3];
    const float* bl = (const float*)d_in[4];
    const float* W  = (const float*)d_in[5];
    const float* b  = (const float*)d_in[6];

    float* h   = (float*)d_out;            // node features live in d_out
    float* agg = (float*)d_ws;             // [N, HID]
    int*   off = (int*)(agg + (size_t)NNODES * HID);  // [N+1] (doubles as histogram)
    int*   cur = off + NNODES + 1;         // [N]
    int*   perm = cur + NNODES;            // [E]

    // Build CSR permutation (dst-grouped edge ids) — reused by all 3 layers.
    hipMemsetAsync(off, 0, (NNODES + 1) * sizeof(int), stream);
    hist_k<<<(NEDGES + 255) / 256, 256, 0, stream>>>(ei, off);
    scan_k<<<1, 1024, 0, stream>>>(off, cur);
    fill_k<<<(NEDGES + 255) / 256, 256, 0, stream>>>(ei, cur, perm);

    for (int l = 0; l < NLAYERS; ++l) {
        const float* hcur = (l == 0) ? x : h;
        agg_k<<<(NNODES + 3) / 4, 256, 0, stream>>>(
            hcur, ei, ea, Wl + (size_t)l * 2 * HID, bl + (size_t)l * HID,
            off, perm, agg);
        gemm_k<<<(NNODES + 63) / 64, 256, 0, stream>>>(
            agg, W + (size_t)l * HID * HID, b + (size_t)l * HID, h);
    }
}

// Round 3
// 502.897 us; speedup vs baseline: 6.4822x; 1.2919x over previous
//
#include <hip/hip_runtime.h>

#define NNODES 50000
#define NEDGES 600000
#define HID 128
#define NLAYERS 3
#define NEG 0.01f

// ---------- CSR build (once per call; edge list is layer-invariant) ----------

__global__ __launch_bounds__(256) void hist_k(const int* __restrict__ ei,
                                              int* __restrict__ deg) {
    const int e = blockIdx.x * blockDim.x + threadIdx.x;
    if (e < NEDGES) atomicAdd(&deg[ei[NEDGES + e]], 1);
}

// Single-block exclusive prefix scan of off[0..NNODES) in place; off[NNODES]=E.
__global__ __launch_bounds__(1024) void scan_k(int* __restrict__ off,
                                               int* __restrict__ cur) {
    __shared__ int s[1024];
    const int t = threadIdx.x;
    int carry = 0;
    for (int base = 0; base < NNODES; base += 1024) {
        const int i = base + t;
        const int v = (i < NNODES) ? off[i] : 0;
        s[t] = v;
        __syncthreads();
        for (int d = 1; d < 1024; d <<= 1) {
            const int add = (t >= d) ? s[t - d] : 0;
            __syncthreads();
            s[t] += add;
            __syncthreads();
        }
        if (i < NNODES) {
            const int excl = carry + s[t] - v;
            off[i] = excl;
            cur[i] = excl;
        }
        const int total = s[1023];
        __syncthreads();
        carry += total;
    }
    if (t == 0) off[NNODES] = carry;
}

// meta[slot] = {src_as_float_bits, a0, a1, 0}, slots grouped by destination.
__global__ __launch_bounds__(256) void fill_k(const int* __restrict__ ei,
                                              const float* __restrict__ ea,
                                              int* __restrict__ cur,
                                              float4* __restrict__ meta) {
    const int e = blockIdx.x * blockDim.x + threadIdx.x;
    if (e < NEDGES) {
        const int s = ei[e];
        const int d = ei[NEDGES + e];
        const float a0 = ea[2 * e];
        const float a1 = ea[2 * e + 1];
        const int p = atomicAdd(&cur[d], 1);
        meta[p] = make_float4(__int_as_float(s), a0, a1, 0.f);
    }
}

// ---------- Aggregation: one wave per node, single indirect load, 4x unroll ----
// agg[n] = h[n] + sum_{incoming e} relu(h[src_e] + ea_e @ Wl + bl)
__global__ __launch_bounds__(256) void agg_k(
    const float* __restrict__ h,
    const float4* __restrict__ meta,
    const float* __restrict__ Wl,   // [2, HID]
    const float* __restrict__ bl,   // [HID]
    const int* __restrict__ off,
    float* __restrict__ agg)
{
    const int node = blockIdx.x * 4 + (threadIdx.x >> 6);
    if (node >= NNODES) return;
    const int lane = threadIdx.x & 63;
    const int f0 = lane << 1;
    const float2 w0 = *(const float2*)(Wl + f0);
    const float2 w1 = *(const float2*)(Wl + HID + f0);
    const float2 bb = *(const float2*)(bl + f0);
    float2 acc = *(const float2*)(h + (size_t)node * HID + f0);  // (1+eps)*h, eps=0
    int idx = off[node];
    const int e1 = off[node + 1];
    for (; idx + 4 <= e1; idx += 4) {
        const float4 m0 = meta[idx + 0];
        const float4 m1 = meta[idx + 1];
        const float4 m2 = meta[idx + 2];
        const float4 m3 = meta[idx + 3];
        const float2 g0 = *(const float2*)(h + (size_t)__float_as_int(m0.x) * HID + f0);
        const float2 g1 = *(const float2*)(h + (size_t)__float_as_int(m1.x) * HID + f0);
        const float2 g2 = *(const float2*)(h + (size_t)__float_as_int(m2.x) * HID + f0);
        const float2 g3 = *(const float2*)(h + (size_t)__float_as_int(m3.x) * HID + f0);
        acc.x += fmaxf(g0.x + fmaf(m0.y, w0.x, fmaf(m0.z, w1.x, bb.x)), 0.f);
        acc.y += fmaxf(g0.y + fmaf(m0.y, w0.y, fmaf(m0.z, w1.y, bb.y)), 0.f);
        acc.x += fmaxf(g1.x + fmaf(m1.y, w0.x, fmaf(m1.z, w1.x, bb.x)), 0.f);
        acc.y += fmaxf(g1.y + fmaf(m1.y, w0.y, fmaf(m1.z, w1.y, bb.y)), 0.f);
        acc.x += fmaxf(g2.x + fmaf(m2.y, w0.x, fmaf(m2.z, w1.x, bb.x)), 0.f);
        acc.y += fmaxf(g2.y + fmaf(m2.y, w0.y, fmaf(m2.z, w1.y, bb.y)), 0.f);
        acc.x += fmaxf(g3.x + fmaf(m3.y, w0.x, fmaf(m3.z, w1.x, bb.x)), 0.f);
        acc.y += fmaxf(g3.y + fmaf(m3.y, w0.y, fmaf(m3.z, w1.y, bb.y)), 0.f);
    }
    for (; idx < e1; ++idx) {
        const float4 m = meta[idx];
        const float2 g = *(const float2*)(h + (size_t)__float_as_int(m.x) * HID + f0);
        acc.x += fmaxf(g.x + fmaf(m.y, w0.x, fmaf(m.z, w1.x, bb.x)), 0.f);
        acc.y += fmaxf(g.y + fmaf(m.y, w0.y, fmaf(m.z, w1.y, bb.y)), 0.f);
    }
    *(float2*)(agg + (size_t)node * HID + f0) = acc;
}

// ---------- Skinny GEMM: out = leakyrelu(v @ W + bias) ----------
__global__ __launch_bounds__(256) void gemm_k(
    const float* __restrict__ v,     // [N, HID]
    const float* __restrict__ W,     // [HID, HID]
    const float* __restrict__ bias,  // [HID]
    float* __restrict__ out)         // [N, HID]
{
    const int tid = threadIdx.x;
    const int row0 = blockIdx.x * 64 + ((tid >> 5) << 3);
    const int f0 = (tid & 31) << 2;
    const float4 bb = *(const float4*)(bias + f0);
    float acc[8][4];
#pragma unroll
    for (int i = 0; i < 8; ++i) {
        acc[i][0] = bb.x; acc[i][1] = bb.y; acc[i][2] = bb.z; acc[i][3] = bb.w;
    }
    for (int k = 0; k < HID; k += 4) {
        const float4 wr0 = *(const float4*)(W + (size_t)(k + 0) * HID + f0);
        const float4 wr1 = *(const float4*)(W + (size_t)(k + 1) * HID + f0);
        const float4 wr2 = *(const float4*)(W + (size_t)(k + 2) * HID + f0);
        const float4 wr3 = *(const float4*)(W + (size_t)(k + 3) * HID + f0);
#pragma unroll
        for (int i = 0; i < 8; ++i) {
            const int r = row0 + i;
            if (r < NNODES) {
                const float4 vv = *(const float4*)(v + (size_t)r * HID + k);
                acc[i][0] = fmaf(vv.x, wr0.x, fmaf(vv.y, wr1.x, fmaf(vv.z, wr2.x, fmaf(vv.w, wr3.x, acc[i][0]))));
                acc[i][1] = fmaf(vv.x, wr0.y, fmaf(vv.y, wr1.y, fmaf(vv.z, wr2.y, fmaf(vv.w, wr3.y, acc[i][1]))));
                acc[i][2] = fmaf(vv.x, wr0.z, fmaf(vv.y, wr1.z, fmaf(vv.z, wr2.z, fmaf(vv.w, wr3.z, acc[i][2]))));
                acc[i][3] = fmaf(vv.x, wr0.w, fmaf(vv.y, wr1.w, fmaf(vv.z, wr2.w, fmaf(vv.w, wr3.w, acc[i][3]))));
            }
        }
    }
#pragma unroll
    for (int i = 0; i < 8; ++i) {
        const int r = row0 + i;
        if (r < NNODES) {
            float4 o;
            o.x = acc[i][0] >= 0.f ? acc[i][0] : NEG * acc[i][0];
            o.y = acc[i][1] >= 0.f ? acc[i][1] : NEG * acc[i][1];
            o.z = acc[i][2] >= 0.f ? acc[i][2] : NEG * acc[i][2];
            o.w = acc[i][3] >= 0.f ? acc[i][3] : NEG * acc[i][3];
            *(float4*)(out + (size_t)r * HID + f0) = o;
        }
    }
}

extern "C" void kernel_launch(void* const* d_in, const int* in_sizes, int n_in,
                              void* d_out, int out_size, void* d_ws, size_t ws_size,
                              hipStream_t stream) {
    const float* x  = (const float*)d_in[0];
    const int*   ei = (const int*)d_in[1];
    const float* ea = (const float*)d_in[2];
    const float* Wl = (const float*)d_in[3];
    const float* bl = (const float*)d_in[4];
    const float* W  = (const float*)d_in[5];
    const float* b  = (const float*)d_in[6];

    float* h    = (float*)d_out;                         // node features
    float* agg  = (float*)d_ws;                          // [N, HID]
    float4* meta = (float4*)(agg + (size_t)NNODES * HID); // [E] {src,a0,a1,_}
    int*   off  = (int*)(meta + NEDGES);                 // [N+1] (doubles as histogram)
    int*   cur  = off + NNODES + 1;                      // [N]

    // Build dst-grouped edge metadata — reused by all 3 layers.
    hipMemsetAsync(off, 0, (NNODES + 1) * sizeof(int), stream);
    hist_k<<<(NEDGES + 255) / 256, 256, 0, stream>>>(ei, off);
    scan_k<<<1, 1024, 0, stream>>>(off, cur);
    fill_k<<<(NEDGES + 255) / 256, 256, 0, stream>>>(ei, ea, cur, meta);

    for (int l = 0; l < NLAYERS; ++l) {
        const float* hcur = (l == 0) ? x : h;
        agg_k<<<(NNODES + 3) / 4, 256, 0, stream>>>(
            hcur, meta, Wl + (size_t)l * 2 * HID, bl + (size_t)l * HID, off, agg);
        gemm_k<<<(NNODES + 63) / 64, 256, 0, stream>>>(
            agg, W + (size_t)l * HID * HID, b + (size_t)l * HID, h);
    }
}

// Round 4
// 496.711 us; speedup vs baseline: 6.5630x; 1.0125x over previous
//
#include <hip/hip_runtime.h>

#define NNODES 50000
#define NEDGES 600000
#define HID 128
#define NLAYERS 3
#define NEG 0.01f
#define SCAN_CH ((NNODES + 1023) / 1024)   // 49 elements per thread

// ---------- CSR build (once per call; edge list is layer-invariant) ----------

__global__ __launch_bounds__(256) void hist_k(const int* __restrict__ ei,
                                              int* __restrict__ deg) {
    const int e = blockIdx.x * blockDim.x + threadIdx.x;
    if (e < NEDGES) atomicAdd(&deg[ei[NEDGES + e]], 1);
}

// Single-block exclusive scan, thread-serial chunks: 2 data passes + one
// 10-step LDS scan of 1024 chunk totals (instead of 490 barriered sweeps).
__global__ __launch_bounds__(1024) void scan_k(int* __restrict__ off,
                                               int* __restrict__ cur) {
    __shared__ int s[1024];
    const int t = threadIdx.x;
    const int i0 = t * SCAN_CH;
    int local[SCAN_CH];
    int sum = 0;
#pragma unroll
    for (int j = 0; j < SCAN_CH; ++j) {
        const int i = i0 + j;
        const int v = (i < NNODES) ? off[i] : 0;
        local[j] = v;
        sum += v;
    }
    s[t] = sum;
    __syncthreads();
    for (int d = 1; d < 1024; d <<= 1) {
        const int add = (t >= d) ? s[t - d] : 0;
        __syncthreads();
        s[t] += add;
        __syncthreads();
    }
    int excl = (t == 0) ? 0 : s[t - 1];
#pragma unroll
    for (int j = 0; j < SCAN_CH; ++j) {
        const int i = i0 + j;
        if (i < NNODES) { off[i] = excl; cur[i] = excl; }
        excl += local[j];
    }
    if (t == 1023) off[NNODES] = excl;  // == grand total (tail chunks are zero)
}

// meta[slot] = {src_as_float_bits, a0, a1, 0}, slots grouped by destination.
__global__ __launch_bounds__(256) void fill_k(const int* __restrict__ ei,
                                              const float* __restrict__ ea,
                                              int* __restrict__ cur,
                                              float4* __restrict__ meta) {
    const int e = blockIdx.x * blockDim.x + threadIdx.x;
    if (e < NEDGES) {
        const int s = ei[e];
        const int d = ei[NEDGES + e];
        const float a0 = ea[2 * e];
        const float a1 = ea[2 * e + 1];
        const int p = atomicAdd(&cur[d], 1);
        meta[p] = make_float4(__int_as_float(s), a0, a1, 0.f);
    }
}

// ---------- Aggregation: one wave per node, single indirect load, 4x unroll ----
// agg[n] = h[n] + sum_{incoming e} relu(h[src_e] + ea_e @ Wl + bl)
__global__ __launch_bounds__(256) void agg_k(
    const float* __restrict__ h,
    const float4* __restrict__ meta,
    const float* __restrict__ Wl,   // [2, HID]
    const float* __restrict__ bl,   // [HID]
    const int* __restrict__ off,
    float* __restrict__ agg)
{
    const int node = blockIdx.x * 4 + (threadIdx.x >> 6);
    if (node >= NNODES) return;
    const int lane = threadIdx.x & 63;
    const int f0 = lane << 1;
    const float2 w0 = *(const float2*)(Wl + f0);
    const float2 w1 = *(const float2*)(Wl + HID + f0);
    const float2 bb = *(const float2*)(bl + f0);
    float2 acc = *(const float2*)(h + (size_t)node * HID + f0);  // (1+eps)*h, eps=0
    int idx = off[node];
    const int e1 = off[node + 1];
    for (; idx + 4 <= e1; idx += 4) {
        const float4 m0 = meta[idx + 0];
        const float4 m1 = meta[idx + 1];
        const float4 m2 = meta[idx + 2];
        const float4 m3 = meta[idx + 3];
        const float2 g0 = *(const float2*)(h + (size_t)__float_as_int(m0.x) * HID + f0);
        const float2 g1 = *(const float2*)(h + (size_t)__float_as_int(m1.x) * HID + f0);
        const float2 g2 = *(const float2*)(h + (size_t)__float_as_int(m2.x) * HID + f0);
        const float2 g3 = *(const float2*)(h + (size_t)__float_as_int(m3.x) * HID + f0);
        acc.x += fmaxf(g0.x + fmaf(m0.y, w0.x, fmaf(m0.z, w1.x, bb.x)), 0.f);
        acc.y += fmaxf(g0.y + fmaf(m0.y, w0.y, fmaf(m0.z, w1.y, bb.y)), 0.f);
        acc.x += fmaxf(g1.x + fmaf(m1.y, w0.x, fmaf(m1.z, w1.x, bb.x)), 0.f);
        acc.y += fmaxf(g1.y + fmaf(m1.y, w0.y, fmaf(m1.z, w1.y, bb.y)), 0.f);
        acc.x += fmaxf(g2.x + fmaf(m2.y, w0.x, fmaf(m2.z, w1.x, bb.x)), 0.f);
        acc.y += fmaxf(g2.y + fmaf(m2.y, w0.y, fmaf(m2.z, w1.y, bb.y)), 0.f);
        acc.x += fmaxf(g3.x + fmaf(m3.y, w0.x, fmaf(m3.z, w1.x, bb.x)), 0.f);
        acc.y += fmaxf(g3.y + fmaf(m3.y, w0.y, fmaf(m3.z, w1.y, bb.y)), 0.f);
    }
    for (; idx < e1; ++idx) {
        const float4 m = meta[idx];
        const float2 g = *(const float2*)(h + (size_t)__float_as_int(m.x) * HID + f0);
        acc.x += fmaxf(g.x + fmaf(m.y, w0.x, fmaf(m.z, w1.x, bb.x)), 0.f);
        acc.y += fmaxf(g.y + fmaf(m.y, w0.y, fmaf(m.z, w1.y, bb.y)), 0.f);
    }
    *(float2*)(agg + (size_t)node * HID + f0) = acc;
}

// ---------- Skinny GEMM: out = leakyrelu(v @ W + bias) ----------
__global__ __launch_bounds__(256) void gemm_k(
    const float* __restrict__ v,     // [N, HID]
    const float* __restrict__ W,     // [HID, HID]
    const float* __restrict__ bias,  // [HID]
    float* __restrict__ out)         // [N, HID]
{
    const int tid = threadIdx.x;
    const int row0 = blockIdx.x * 64 + ((tid >> 5) << 3);
    const int f0 = (tid & 31) << 2;
    const float4 bb = *(const float4*)(bias + f0);
    float acc[8][4];
#pragma unroll
    for (int i = 0; i < 8; ++i) {
        acc[i][0] = bb.x; acc[i][1] = bb.y; acc[i][2] = bb.z; acc[i][3] = bb.w;
    }
    for (int k = 0; k < HID; k += 4) {
        const float4 wr0 = *(const float4*)(W + (size_t)(k + 0) * HID + f0);
        const float4 wr1 = *(const float4*)(W + (size_t)(k + 1) * HID + f0);
        const float4 wr2 = *(const float4*)(W + (size_t)(k + 2) * HID + f0);
        const float4 wr3 = *(const float4*)(W + (size_t)(k + 3) * HID + f0);
#pragma unroll
        for (int i = 0; i < 8; ++i) {
            const int r = row0 + i;
            if (r < NNODES) {
                const float4 vv = *(const float4*)(v + (size_t)r * HID + k);
                acc[i][0] = fmaf(vv.x, wr0.x, fmaf(vv.y, wr1.x, fmaf(vv.z, wr2.x, fmaf(vv.w, wr3.x, acc[i][0]))));
                acc[i][1] = fmaf(vv.x, wr0.y, fmaf(vv.y, wr1.y, fmaf(vv.z, wr2.y, fmaf(vv.w, wr3.y, acc[i][1]))));
                acc[i][2] = fmaf(vv.x, wr0.z, fmaf(vv.y, wr1.z, fmaf(vv.z, wr2.z, fmaf(vv.w, wr3.z, acc[i][2]))));
                acc[i][3] = fmaf(vv.x, wr0.w, fmaf(vv.y, wr1.w, fmaf(vv.z, wr2.w, fmaf(vv.w, wr3.w, acc[i][3]))));
            }
        }
    }
#pragma unroll
    for (int i = 0; i < 8; ++i) {
        const int r = row0 + i;
        if (r < NNODES) {
            float4 o;
            o.x = acc[i][0] >= 0.f ? acc[i][0] : NEG * acc[i][0];
            o.y = acc[i][1] >= 0.f ? acc[i][1] : NEG * acc[i][1];
            o.z = acc[i][2] >= 0.f ? acc[i][2] : NEG * acc[i][2];
            o.w = acc[i][3] >= 0.f ? acc[i][3] : NEG * acc[i][3];
            *(float4*)(out + (size_t)r * HID + f0) = o;
        }
    }
}

extern "C" void kernel_launch(void* const* d_in, const int* in_sizes, int n_in,
                              void* d_out, int out_size, void* d_ws, size_t ws_size,
                              hipStream_t stream) {
    const float* x  = (const float*)d_in[0];
    const int*   ei = (const int*)d_in[1];
    const float* ea = (const float*)d_in[2];
    const float* Wl = (const float*)d_in[3];
    const float* bl = (const float*)d_in[4];
    const float* W  = (const float*)d_in[5];
    const float* b  = (const float*)d_in[6];

    float* h    = (float*)d_out;                          // node features
    float* agg  = (float*)d_ws;                           // [N, HID]
    float4* meta = (float4*)(agg + (size_t)NNODES * HID); // [E] {src,a0,a1,_}
    int*   off  = (int*)(meta + NEDGES);                  // [N+1] (doubles as histogram)
    int*   cur  = off + NNODES + 1;                       // [N]

    // Build dst-grouped edge metadata — reused by all 3 layers.
    hipMemsetAsync(off, 0, (NNODES + 1) * sizeof(int), stream);
    hist_k<<<(NEDGES + 255) / 256, 256, 0, stream>>>(ei, off);
    scan_k<<<1, 1024, 0, stream>>>(off, cur);
    fill_k<<<(NEDGES + 255) / 256, 256, 0, stream>>>(ei, ea, cur, meta);

    for (int l = 0; l < NLAYERS; ++l) {
        const float* hcur = (l == 0) ? x : h;
        agg_k<<<(NNODES + 3) / 4, 256, 0, stream>>>(
            hcur, meta, Wl + (size_t)l * 2 * HID, bl + (size_t)l * HID, off, agg);
        gemm_k<<<(NNODES + 63) / 64, 256, 0, stream>>>(
            agg, W + (size_t)l * HID * HID, b + (size_t)l * HID, h);
    }
}

// Round 5
// 422.832 us; speedup vs baseline: 7.7097x; 1.1747x over previous
//
#include <hip/hip_runtime.h>

#define NNODES 50000
#define NEDGES 600000
#define HID 128
#define NLAYERS 3
#define NEG 0.01f
#define SCAN_B ((NNODES + 1023) / 1024)   // 49 blocks

// ---------- CSR build (once per call; edge list is layer-invariant) ----------

__global__ __launch_bounds__(256) void hist_k(const int* __restrict__ ei,
                                              int* __restrict__ deg) {
    const int e = blockIdx.x * blockDim.x + threadIdx.x;
    if (e < NEDGES) atomicAdd(&deg[ei[NEDGES + e]], 1);
}

// Hierarchical exclusive scan, stage 1: per-block LDS scan (coalesced).
__global__ __launch_bounds__(1024) void scan1_k(const int* __restrict__ deg,
                                                int* __restrict__ part,
                                                int* __restrict__ bsum) {
    __shared__ int s[1024];
    const int t = threadIdx.x;
    const int i = blockIdx.x * 1024 + t;
    const int v = (i < NNODES) ? deg[i] : 0;
    s[t] = v;
    __syncthreads();
    for (int d = 1; d < 1024; d <<= 1) {
        const int add = (t >= d) ? s[t - d] : 0;
        __syncthreads();
        s[t] += add;
        __syncthreads();
    }
    if (i < NNODES) part[i] = s[t] - v;          // block-local exclusive
    if (t == 1023) bsum[blockIdx.x] = s[1023];   // block total
}

// Stage 2: add cross-block prefix (wave-reduce of bsum[0..b), b<=48<64 lanes).
__global__ __launch_bounds__(1024) void scan2_k(const int* __restrict__ part,
                                                const int* __restrict__ bsum,
                                                int* __restrict__ off,
                                                int* __restrict__ cur) {
    const int b = blockIdx.x;
    const int t = threadIdx.x;
    const int lane = t & 63;
    int v = (lane < b) ? bsum[lane] : 0;
#pragma unroll
    for (int d = 1; d < 64; d <<= 1) v += __shfl_xor(v, d);
    const int i = b * 1024 + t;
    if (i < NNODES) {
        const int e = part[i] + v;
        off[i] = e;
        cur[i] = e;
    }
    if (b == 0 && t == 0) off[NNODES] = NEDGES;
}

// meta[slot] = {src_as_float_bits, a0, a1, 0}, slots grouped by destination.
__global__ __launch_bounds__(256) void fill_k(const int* __restrict__ ei,
                                              const float* __restrict__ ea,
                                              int* __restrict__ cur,
                                              float4* __restrict__ meta) {
    const int e = blockIdx.x * blockDim.x + threadIdx.x;
    if (e < NEDGES) {
        const int s = ei[e];
        const int d = ei[NEDGES + e];
        const float a0 = ea[2 * e];
        const float a1 = ea[2 * e + 1];
        const int p = atomicAdd(&cur[d], 1);
        meta[p] = make_float4(__int_as_float(s), a0, a1, 0.f);
    }
}

// ---------- Aggregation: one wave per node, single indirect load, 4x unroll ----
// agg[n] = h[n] + sum_{incoming e} relu(h[src_e] + ea_e @ Wl + bl)
__global__ __launch_bounds__(256) void agg_k(
    const float* __restrict__ h,
    const float4* __restrict__ meta,
    const float* __restrict__ Wl,   // [2, HID]
    const float* __restrict__ bl,   // [HID]
    const int* __restrict__ off,
    float* __restrict__ agg)
{
    const int node = blockIdx.x * 4 + (threadIdx.x >> 6);
    if (node >= NNODES) return;
    const int lane = threadIdx.x & 63;
    const int f0 = lane << 1;
    const float2 w0 = *(const float2*)(Wl + f0);
    const float2 w1 = *(const float2*)(Wl + HID + f0);
    const float2 bb = *(const float2*)(bl + f0);
    float2 acc = *(const float2*)(h + (size_t)node * HID + f0);  // (1+eps)*h, eps=0
    int idx = off[node];
    const int e1 = off[node + 1];
    for (; idx + 4 <= e1; idx += 4) {
        const float4 m0 = meta[idx + 0];
        const float4 m1 = meta[idx + 1];
        const float4 m2 = meta[idx + 2];
        const float4 m3 = meta[idx + 3];
        const float2 g0 = *(const float2*)(h + (size_t)__float_as_int(m0.x) * HID + f0);
        const float2 g1 = *(const float2*)(h + (size_t)__float_as_int(m1.x) * HID + f0);
        const float2 g2 = *(const float2*)(h + (size_t)__float_as_int(m2.x) * HID + f0);
        const float2 g3 = *(const float2*)(h + (size_t)__float_as_int(m3.x) * HID + f0);
        acc.x += fmaxf(g0.x + fmaf(m0.y, w0.x, fmaf(m0.z, w1.x, bb.x)), 0.f);
        acc.y += fmaxf(g0.y + fmaf(m0.y, w0.y, fmaf(m0.z, w1.y, bb.y)), 0.f);
        acc.x += fmaxf(g1.x + fmaf(m1.y, w0.x, fmaf(m1.z, w1.x, bb.x)), 0.f);
        acc.y += fmaxf(g1.y + fmaf(m1.y, w0.y, fmaf(m1.z, w1.y, bb.y)), 0.f);
        acc.x += fmaxf(g2.x + fmaf(m2.y, w0.x, fmaf(m2.z, w1.x, bb.x)), 0.f);
        acc.y += fmaxf(g2.y + fmaf(m2.y, w0.y, fmaf(m2.z, w1.y, bb.y)), 0.f);
        acc.x += fmaxf(g3.x + fmaf(m3.y, w0.x, fmaf(m3.z, w1.x, bb.x)), 0.f);
        acc.y += fmaxf(g3.y + fmaf(m3.y, w0.y, fmaf(m3.z, w1.y, bb.y)), 0.f);
    }
    for (; idx < e1; ++idx) {
        const float4 m = meta[idx];
        const float2 g = *(const float2*)(h + (size_t)__float_as_int(m.x) * HID + f0);
        acc.x += fmaxf(g.x + fmaf(m.y, w0.x, fmaf(m.z, w1.x, bb.x)), 0.f);
        acc.y += fmaxf(g.y + fmaf(m.y, w0.y, fmaf(m.z, w1.y, bb.y)), 0.f);
    }
    *(float2*)(agg + (size_t)node * HID + f0) = acc;
}

// ---------- Skinny GEMM: out = leakyrelu(v @ W + bias) ----------
__global__ __launch_bounds__(256) void gemm_k(
    const float* __restrict__ v,     // [N, HID]
    const float* __restrict__ W,     // [HID, HID]
    const float* __restrict__ bias,  // [HID]
    float* __restrict__ out)         // [N, HID]
{
    const int tid = threadIdx.x;
    const int row0 = blockIdx.x * 64 + ((tid >> 5) << 3);
    const int f0 = (tid & 31) << 2;
    const float4 bb = *(const float4*)(bias + f0);
    float acc[8][4];
#pragma unroll
    for (int i = 0; i < 8; ++i) {
        acc[i][0] = bb.x; acc[i][1] = bb.y; acc[i][2] = bb.z; acc[i][3] = bb.w;
    }
    for (int k = 0; k < HID; k += 4) {
        const float4 wr0 = *(const float4*)(W + (size_t)(k + 0) * HID + f0);
        const float4 wr1 = *(const float4*)(W + (size_t)(k + 1) * HID + f0);
        const float4 wr2 = *(const float4*)(W + (size_t)(k + 2) * HID + f0);
        const float4 wr3 = *(const float4*)(W + (size_t)(k + 3) * HID + f0);
#pragma unroll
        for (int i = 0; i < 8; ++i) {
            const int r = row0 + i;
            if (r < NNODES) {
                const float4 vv = *(const float4*)(v + (size_t)r * HID + k);
                acc[i][0] = fmaf(vv.x, wr0.x, fmaf(vv.y, wr1.x, fmaf(vv.z, wr2.x, fmaf(vv.w, wr3.x, acc[i][0]))));
                acc[i][1] = fmaf(vv.x, wr0.y, fmaf(vv.y, wr1.y, fmaf(vv.z, wr2.y, fmaf(vv.w, wr3.y, acc[i][1]))));
                acc[i][2] = fmaf(vv.x, wr0.z, fmaf(vv.y, wr1.z, fmaf(vv.z, wr2.z, fmaf(vv.w, wr3.z, acc[i][2]))));
                acc[i][3] = fmaf(vv.x, wr0.w, fmaf(vv.y, wr1.w, fmaf(vv.z, wr2.w, fmaf(vv.w, wr3.w, acc[i][3]))));
            }
        }
    }
#pragma unroll
    for (int i = 0; i < 8; ++i) {
        const int r = row0 + i;
        if (r < NNODES) {
            float4 o;
            o.x = acc[i][0] >= 0.f ? acc[i][0] : NEG * acc[i][0];
            o.y = acc[i][1] >= 0.f ? acc[i][1] : NEG * acc[i][1];
            o.z = acc[i][2] >= 0.f ? acc[i][2] : NEG * acc[i][2];
            o.w = acc[i][3] >= 0.f ? acc[i][3] : NEG * acc[i][3];
            *(float4*)(out + (size_t)r * HID + f0) = o;
        }
    }
}

extern "C" void kernel_launch(void* const* d_in, const int* in_sizes, int n_in,
                              void* d_out, int out_size, void* d_ws, size_t ws_size,
                              hipStream_t stream) {
    const float* x  = (const float*)d_in[0];
    const int*   ei = (const int*)d_in[1];
    const float* ea = (const float*)d_in[2];
    const float* Wl = (const float*)d_in[3];
    const float* bl = (const float*)d_in[4];
    const float* W  = (const float*)d_in[5];
    const float* b  = (const float*)d_in[6];

    float* h    = (float*)d_out;                          // node features
    float* agg  = (float*)d_ws;                           // [N, HID]
    float4* meta = (float4*)(agg + (size_t)NNODES * HID); // [E] {src,a0,a1,_}
    int*   off  = (int*)(meta + NEDGES);                  // [N+1] (doubles as histogram)
    int*   cur  = off + NNODES + 1;                       // [N]
    int*   part = cur + NNODES;                           // [N] scan partials
    int*   bsum = part + NNODES;                          // [SCAN_B]

    // Build dst-grouped edge metadata — reused by all 3 layers.
    hipMemsetAsync(off, 0, (NNODES + 1) * sizeof(int), stream);
    hist_k<<<(NEDGES + 255) / 256, 256, 0, stream>>>(ei, off);
    scan1_k<<<SCAN_B, 1024, 0, stream>>>(off, part, bsum);
    scan2_k<<<SCAN_B, 1024, 0, stream>>>(part, bsum, off, cur);
    fill_k<<<(NEDGES + 255) / 256, 256, 0, stream>>>(ei, ea, cur, meta);

    for (int l = 0; l < NLAYERS; ++l) {
        const float* hcur = (l == 0) ? x : h;
        agg_k<<<(NNODES + 3) / 4, 256, 0, stream>>>(
            hcur, meta, Wl + (size_t)l * 2 * HID, bl + (size_t)l * HID, off, agg);
        gemm_k<<<(NNODES + 63) / 64, 256, 0, stream>>>(
            agg, W + (size_t)l * HID * HID, b + (size_t)l * HID, h);
    }
}

// Round 6
// 284.315 us; speedup vs baseline: 11.4658x; 1.4872x over previous
//
#include <hip/hip_runtime.h>

#define NNODES 50000
#define NEDGES 600000
#define HID 128
#define NLAYERS 3
#define NEG 0.01f
#define SCAN_B ((NNODES + 1023) / 1024)   // 49 blocks

typedef __attribute__((ext_vector_type(8))) short short8;
typedef __attribute__((ext_vector_type(4))) float f32x4;

__device__ __forceinline__ unsigned int f2bf(float f) {   // RNE f32 -> bf16 bits
    unsigned int u = __float_as_uint(f);
    return (u + 0x7fffu + ((u >> 16) & 1u)) >> 16;
}
__device__ __forceinline__ float bf2f(unsigned int h) {
    return __uint_as_float(h << 16);
}

// ---------- CSR build (once per call; edge list is layer-invariant) ----------

__global__ __launch_bounds__(256) void hist_k(const int* __restrict__ ei,
                                              int* __restrict__ deg) {
    const int e = blockIdx.x * blockDim.x + threadIdx.x;
    if (e < NEDGES) atomicAdd(&deg[ei[NEDGES + e]], 1);
}

__global__ __launch_bounds__(1024) void scan1_k(const int* __restrict__ deg,
                                                int* __restrict__ part,
                                                int* __restrict__ bsum) {
    __shared__ int s[1024];
    const int t = threadIdx.x;
    const int i = blockIdx.x * 1024 + t;
    const int v = (i < NNODES) ? deg[i] : 0;
    s[t] = v;
    __syncthreads();
    for (int d = 1; d < 1024; d <<= 1) {
        const int add = (t >= d) ? s[t - d] : 0;
        __syncthreads();
        s[t] += add;
        __syncthreads();
    }
    if (i < NNODES) part[i] = s[t] - v;
    if (t == 1023) bsum[blockIdx.x] = s[1023];
}

__global__ __launch_bounds__(1024) void scan2_k(const int* __restrict__ part,
                                                const int* __restrict__ bsum,
                                                int* __restrict__ off,
                                                int* __restrict__ cur) {
    const int b = blockIdx.x;
    const int t = threadIdx.x;
    const int lane = t & 63;
    int v = (lane < b) ? bsum[lane] : 0;
#pragma unroll
    for (int d = 1; d < 64; d <<= 1) v += __shfl_xor(v, d);
    const int i = b * 1024 + t;
    if (i < NNODES) {
        const int e = part[i] + v;
        off[i] = e;
        cur[i] = e;
    }
    if (b == 0 && t == 0) off[NNODES] = NEDGES;
}

__global__ __launch_bounds__(256) void fill_k(const int* __restrict__ ei,
                                              const float* __restrict__ ea,
                                              int* __restrict__ cur,
                                              float4* __restrict__ meta) {
    const int e = blockIdx.x * blockDim.x + threadIdx.x;
    if (e < NEDGES) {
        const int s = ei[e];
        const int d = ei[NEDGES + e];
        const float a0 = ea[2 * e];
        const float a1 = ea[2 * e + 1];
        const int p = atomicAdd(&cur[d], 1);
        meta[p] = make_float4(__int_as_float(s), a0, a1, 0.f);
    }
}

// ---------- W -> split-bf16 MFMA B-fragment layout (once, all layers) --------
// Fragment element (k, n): k = kt*32 + (lane>>4)*8 + j, n = nt*16 + (lane&15).
// whf/wlf index: (((l*4 + kt)*8 + nt)*64 + lane) as uint4 (8 bf16).
__global__ __launch_bounds__(256) void wconv_k(const float* __restrict__ W,
                                               uint4* __restrict__ whf,
                                               uint4* __restrict__ wlf) {
    const int g = (blockIdx.x * 256 + threadIdx.x) >> 6;
    if (g >= NLAYERS * 32) return;
    const int lane = threadIdx.x & 63;
    const int l = g >> 5;
    const int kt = (g >> 3) & 3;
    const int nt = g & 7;
    const int n = nt * 16 + (lane & 15);
    const int k0 = kt * 32 + (lane >> 4) * 8;
    unsigned int hh[8], ll[8];
#pragma unroll
    for (int j = 0; j < 8; ++j) {
        const float w = W[l * HID * HID + (k0 + j) * HID + n];
        const unsigned int wh = f2bf(w);
        hh[j] = wh;
        ll[j] = f2bf(w - bf2f(wh));
    }
    uint4 ph, pl;
    ph.x = hh[0] | (hh[1] << 16); ph.y = hh[2] | (hh[3] << 16);
    ph.z = hh[4] | (hh[5] << 16); ph.w = hh[6] | (hh[7] << 16);
    pl.x = ll[0] | (ll[1] << 16); pl.y = ll[2] | (ll[3] << 16);
    pl.z = ll[4] | (ll[5] << 16); pl.w = ll[6] | (ll[7] << 16);
    const int idx = ((l * 4 + kt) * 8 + nt) * 64 + lane;
    whf[idx] = ph;
    wlf[idx] = pl;
}

// ---------- Aggregation: one wave per node; emits packed bf16 GEMM input -----
// vh[n] = bf16( h[n] + sum_{incoming e} relu(h[src_e] + ea_e @ Wl + bl) )
__global__ __launch_bounds__(256) void agg_k(
    const float* __restrict__ h,
    const float4* __restrict__ meta,
    const float* __restrict__ Wl,   // [2, HID]
    const float* __restrict__ bl,   // [HID]
    const int* __restrict__ off,
    unsigned int* __restrict__ vh)  // [N*64] packed bf16x2
{
    const int node = blockIdx.x * 4 + (threadIdx.x >> 6);
    if (node >= NNODES) return;
    const int lane = threadIdx.x & 63;
    const int f0 = lane << 1;
    const float2 w0 = *(const float2*)(Wl + f0);
    const float2 w1 = *(const float2*)(Wl + HID + f0);
    const float2 bb = *(const float2*)(bl + f0);
    float2 acc = *(const float2*)(h + (size_t)node * HID + f0);  // (1+eps)*h, eps=0
    int idx = off[node];
    const int e1 = off[node + 1];
    for (; idx + 4 <= e1; idx += 4) {
        const float4 m0 = meta[idx + 0];
        const float4 m1 = meta[idx + 1];
        const float4 m2 = meta[idx + 2];
        const float4 m3 = meta[idx + 3];
        const float2 g0 = *(const float2*)(h + (size_t)__float_as_int(m0.x) * HID + f0);
        const float2 g1 = *(const float2*)(h + (size_t)__float_as_int(m1.x) * HID + f0);
        const float2 g2 = *(const float2*)(h + (size_t)__float_as_int(m2.x) * HID + f0);
        const float2 g3 = *(const float2*)(h + (size_t)__float_as_int(m3.x) * HID + f0);
        acc.x += fmaxf(g0.x + fmaf(m0.y, w0.x, fmaf(m0.z, w1.x, bb.x)), 0.f);
        acc.y += fmaxf(g0.y + fmaf(m0.y, w0.y, fmaf(m0.z, w1.y, bb.y)), 0.f);
        acc.x += fmaxf(g1.x + fmaf(m1.y, w0.x, fmaf(m1.z, w1.x, bb.x)), 0.f);
        acc.y += fmaxf(g1.y + fmaf(m1.y, w0.y, fmaf(m1.z, w1.y, bb.y)), 0.f);
        acc.x += fmaxf(g2.x + fmaf(m2.y, w0.x, fmaf(m2.z, w1.x, bb.x)), 0.f);
        acc.y += fmaxf(g2.y + fmaf(m2.y, w0.y, fmaf(m2.z, w1.y, bb.y)), 0.f);
        acc.x += fmaxf(g3.x + fmaf(m3.y, w0.x, fmaf(m3.z, w1.x, bb.x)), 0.f);
        acc.y += fmaxf(g3.y + fmaf(m3.y, w0.y, fmaf(m3.z, w1.y, bb.y)), 0.f);
    }
    for (; idx < e1; ++idx) {
        const float4 m = meta[idx];
        const float2 g = *(const float2*)(h + (size_t)__float_as_int(m.x) * HID + f0);
        acc.x += fmaxf(g.x + fmaf(m.y, w0.x, fmaf(m.z, w1.x, bb.x)), 0.f);
        acc.y += fmaxf(g.y + fmaf(m.y, w0.y, fmaf(m.z, w1.y, bb.y)), 0.f);
    }
    vh[(size_t)node * 64 + lane] = f2bf(acc.x) | (f2bf(acc.y) << 16);
}

// ---------- MFMA GEMM: out = leakyrelu(bf16(v) @ (wh+wl) + bias), f32 out ----
// Block = 256 thr = 4 waves; wave = 16 rows x 128 cols; 8 MFMAs per col-tile.
__global__ __launch_bounds__(256) void gemm_k(
    const unsigned int* __restrict__ vh,   // [N][128] bf16 (packed x2)
    const uint4* __restrict__ whf,         // this layer's [4][8][64] frags
    const uint4* __restrict__ wlf,
    const float* __restrict__ bias,        // [HID]
    float* __restrict__ out)               // [N, HID] f32
{
    const int tid = threadIdx.x;
    const int wave = tid >> 6;
    const int lane = tid & 63;
    const int rowbase = blockIdx.x * 64 + wave * 16;
    const int arow = rowbase + (lane & 15);
    const int arowc = arow < NNODES ? arow : NNODES - 1;   // clamp loads; guard stores
    const uint4* vh4 = (const uint4*)vh;                   // 16 uint4 per row

    short8 a[4];
#pragma unroll
    for (int kt = 0; kt < 4; ++kt) {
        uint4 t = vh4[(size_t)arowc * 16 + kt * 4 + (lane >> 4)];
        a[kt] = *(short8*)&t;
    }

    const int crow0 = rowbase + (lane >> 4) * 4;
    const int ncol = lane & 15;
#pragma unroll
    for (int nt = 0; nt < 8; ++nt) {
        const float bv = bias[nt * 16 + ncol];
        f32x4 acc = {bv, bv, bv, bv};
#pragma unroll
        for (int kt = 0; kt < 4; ++kt) {
            uint4 th = whf[(kt * 8 + nt) * 64 + lane];
            uint4 tl = wlf[(kt * 8 + nt) * 64 + lane];
            acc = __builtin_amdgcn_mfma_f32_16x16x32_bf16(a[kt], *(short8*)&th, acc, 0, 0, 0);
            acc = __builtin_amdgcn_mfma_f32_16x16x32_bf16(a[kt], *(short8*)&tl, acc, 0, 0, 0);
        }
#pragma unroll
        for (int r = 0; r < 4; ++r) {
            const int rr = crow0 + r;
            if (rr < NNODES) {
                float v = acc[r];
                v = v >= 0.f ? v : NEG * v;
                out[(size_t)rr * HID + nt * 16 + ncol] = v;
            }
        }
    }
}

extern "C" void kernel_launch(void* const* d_in, const int* in_sizes, int n_in,
                              void* d_out, int out_size, void* d_ws, size_t ws_size,
                              hipStream_t stream) {
    const float* x  = (const float*)d_in[0];
    const int*   ei = (const int*)d_in[1];
    const float* ea = (const float*)d_in[2];
    const float* Wl = (const float*)d_in[3];
    const float* bl = (const float*)d_in[4];
    const float* W  = (const float*)d_in[5];
    const float* b  = (const float*)d_in[6];

    float* h = (float*)d_out;                              // node features (f32)

    float4* meta = (float4*)d_ws;                          // [E] {src,a0,a1,_}
    unsigned int* vh = (unsigned int*)(meta + NEDGES);     // [N*64] bf16x2 GEMM input
    uint4* whf = (uint4*)(vh + (size_t)NNODES * 64);       // [3][4][8][64]
    uint4* wlf = whf + NLAYERS * 4 * 8 * 64;
    int* off  = (int*)(wlf + NLAYERS * 4 * 8 * 64);        // [N+1] (doubles as histogram)
    int* cur  = off + NNODES + 1;
    int* part = cur + NNODES;
    int* bsum = part + NNODES;

    // CSR metadata + W fragments — reused by all 3 layers.
    hipMemsetAsync(off, 0, (NNODES + 1) * sizeof(int), stream);
    hist_k<<<(NEDGES + 255) / 256, 256, 0, stream>>>(ei, off);
    scan1_k<<<SCAN_B, 1024, 0, stream>>>(off, part, bsum);
    scan2_k<<<SCAN_B, 1024, 0, stream>>>(part, bsum, off, cur);
    fill_k<<<(NEDGES + 255) / 256, 256, 0, stream>>>(ei, ea, cur, meta);
    wconv_k<<<24, 256, 0, stream>>>(W, whf, wlf);

    for (int l = 0; l < NLAYERS; ++l) {
        const float* hcur = (l == 0) ? x : h;
        agg_k<<<(NNODES + 3) / 4, 256, 0, stream>>>(
            hcur, meta, Wl + (size_t)l * 2 * HID, bl + (size_t)l * HID, off, vh);
        gemm_k<<<(NNODES + 63) / 64, 256, 0, stream>>>(
            vh, whf + (size_t)l * 4 * 8 * 64, wlf + (size_t)l * 4 * 8 * 64,
            b + (size_t)l * HID, h);
    }
}

// Round 7
// 252.295 us; speedup vs baseline: 12.9210x; 1.1269x over previous
//
#include <hip/hip_runtime.h>

#define NNODES 50000
#define NEDGES 600000
#define HID 128
#define NLAYERS 3
#define NEG 0.01f
#define SCAN_B ((NNODES + 1023) / 1024)   // 49 blocks

typedef __attribute__((ext_vector_type(8))) short short8;
typedef __attribute__((ext_vector_type(4))) float f32x4;

__device__ __forceinline__ unsigned int f2bf(float f) {   // RNE f32 -> bf16 bits
    unsigned int u = __float_as_uint(f);
    return (u + 0x7fffu + ((u >> 16) & 1u)) >> 16;
}
__device__ __forceinline__ float bf2f(unsigned int h) {
    return __uint_as_float(h << 16);
}
__device__ __forceinline__ float bflo(unsigned int p) { return __uint_as_float(p << 16); }
__device__ __forceinline__ float bfhi(unsigned int p) { return __uint_as_float(p & 0xffff0000u); }

// ---------- CSR build (once per call; edge list is layer-invariant) ----------

__global__ __launch_bounds__(256) void hist_k(const int* __restrict__ ei,
                                              int* __restrict__ deg) {
    const int e = blockIdx.x * blockDim.x + threadIdx.x;
    if (e < NEDGES) atomicAdd(&deg[ei[NEDGES + e]], 1);
}

__global__ __launch_bounds__(1024) void scan1_k(const int* __restrict__ deg,
                                                int* __restrict__ part,
                                                int* __restrict__ bsum) {
    __shared__ int s[1024];
    const int t = threadIdx.x;
    const int i = blockIdx.x * 1024 + t;
    const int v = (i < NNODES) ? deg[i] : 0;
    s[t] = v;
    __syncthreads();
    for (int d = 1; d < 1024; d <<= 1) {
        const int add = (t >= d) ? s[t - d] : 0;
        __syncthreads();
        s[t] += add;
        __syncthreads();
    }
    if (i < NNODES) part[i] = s[t] - v;
    if (t == 1023) bsum[blockIdx.x] = s[1023];
}

__global__ __launch_bounds__(1024) void scan2_k(const int* __restrict__ part,
                                                const int* __restrict__ bsum,
                                                int* __restrict__ off,
                                                int* __restrict__ cur) {
    const int b = blockIdx.x;
    const int t = threadIdx.x;
    const int lane = t & 63;
    int v = (lane < b) ? bsum[lane] : 0;
#pragma unroll
    for (int d = 1; d < 64; d <<= 1) v += __shfl_xor(v, d);
    const int i = b * 1024 + t;
    if (i < NNODES) {
        const int e = part[i] + v;
        off[i] = e;
        cur[i] = e;
    }
    if (b == 0 && t == 0) off[NNODES] = NEDGES;
}

__global__ __launch_bounds__(256) void fill_k(const int* __restrict__ ei,
                                              const float* __restrict__ ea,
                                              int* __restrict__ cur,
                                              float4* __restrict__ meta) {
    const int e = blockIdx.x * blockDim.x + threadIdx.x;
    if (e < NEDGES) {
        const int s = ei[e];
        const int d = ei[NEDGES + e];
        const float a0 = ea[2 * e];
        const float a1 = ea[2 * e + 1];
        const int p = atomicAdd(&cur[d], 1);
        meta[p] = make_float4(__int_as_float(s), a0, a1, 0.f);
    }
}

// x (f32) -> hb (bf16 packed x2), layer-0 node features.
__global__ __launch_bounds__(256) void cvt_k(const float* __restrict__ x,
                                             unsigned int* __restrict__ hb) {
    const int i = blockIdx.x * 256 + threadIdx.x;
    if (i < NNODES * 64) {
        const float2 v = *(const float2*)(x + (size_t)i * 2);
        hb[i] = f2bf(v.x) | (f2bf(v.y) << 16);
    }
}

// ---------- W -> split-bf16 MFMA B-fragment layout (once, all layers) --------
__global__ __launch_bounds__(256) void wconv_k(const float* __restrict__ W,
                                               uint4* __restrict__ whf,
                                               uint4* __restrict__ wlf) {
    const int g = (blockIdx.x * 256 + threadIdx.x) >> 6;
    if (g >= NLAYERS * 32) return;
    const int lane = threadIdx.x & 63;
    const int l = g >> 5;
    const int kt = (g >> 3) & 3;
    const int nt = g & 7;
    const int n = nt * 16 + (lane & 15);
    const int k0 = kt * 32 + (lane >> 4) * 8;
    unsigned int hh[8], ll[8];
#pragma unroll
    for (int j = 0; j < 8; ++j) {
        const float w = W[l * HID * HID + (k0 + j) * HID + n];
        const unsigned int wh = f2bf(w);
        hh[j] = wh;
        ll[j] = f2bf(w - bf2f(wh));
    }
    uint4 ph, pl;
    ph.x = hh[0] | (hh[1] << 16); ph.y = hh[2] | (hh[3] << 16);
    ph.z = hh[4] | (hh[5] << 16); ph.w = hh[6] | (hh[7] << 16);
    pl.x = ll[0] | (ll[1] << 16); pl.y = ll[2] | (ll[3] << 16);
    pl.z = ll[4] | (ll[5] << 16); pl.w = ll[6] | (ll[7] << 16);
    const int idx = ((l * 4 + kt) * 8 + nt) * 64 + lane;
    whf[idx] = ph;
    wlf[idx] = pl;
}

// ---------- Aggregation: one wave per node, bf16 gathers, 8-deep MLP ---------
// vh[n] = bf16( h[n] + sum_{incoming e} relu(h[src_e] + ea_e @ Wl + bl) )
__global__ __launch_bounds__(256) void agg_k(
    const unsigned int* __restrict__ hb,  // [N*64] bf16x2 node features
    const float4* __restrict__ meta,
    const float* __restrict__ Wl,   // [2, HID]
    const float* __restrict__ bl,   // [HID]
    const int* __restrict__ off,
    unsigned int* __restrict__ vh)  // [N*64] packed bf16x2
{
    const int node = blockIdx.x * 4 + (threadIdx.x >> 6);
    if (node >= NNODES) return;
    const int lane = threadIdx.x & 63;
    const int f0 = lane << 1;
    const float2 w0 = *(const float2*)(Wl + f0);
    const float2 w1 = *(const float2*)(Wl + HID + f0);
    const float2 bb = *(const float2*)(bl + f0);
    const unsigned int hp = hb[(size_t)node * 64 + lane];
    float2 acc = make_float2(bflo(hp), bfhi(hp));   // (1+eps)*h, eps=0
    int idx = off[node];
    const int e1 = off[node + 1];
    for (; idx + 8 <= e1; idx += 8) {
        float4 m[8];
#pragma unroll
        for (int j = 0; j < 8; ++j) m[j] = meta[idx + j];
        unsigned int g[8];
#pragma unroll
        for (int j = 0; j < 8; ++j)
            g[j] = hb[(size_t)__float_as_int(m[j].x) * 64 + lane];
#pragma unroll
        for (int j = 0; j < 8; ++j) {
            acc.x += fmaxf(bflo(g[j]) + fmaf(m[j].y, w0.x, fmaf(m[j].z, w1.x, bb.x)), 0.f);
            acc.y += fmaxf(bfhi(g[j]) + fmaf(m[j].y, w0.y, fmaf(m[j].z, w1.y, bb.y)), 0.f);
        }
    }
    if (idx + 4 <= e1) {
        float4 m[4];
#pragma unroll
        for (int j = 0; j < 4; ++j) m[j] = meta[idx + j];
        unsigned int g[4];
#pragma unroll
        for (int j = 0; j < 4; ++j)
            g[j] = hb[(size_t)__float_as_int(m[j].x) * 64 + lane];
#pragma unroll
        for (int j = 0; j < 4; ++j) {
            acc.x += fmaxf(bflo(g[j]) + fmaf(m[j].y, w0.x, fmaf(m[j].z, w1.x, bb.x)), 0.f);
            acc.y += fmaxf(bfhi(g[j]) + fmaf(m[j].y, w0.y, fmaf(m[j].z, w1.y, bb.y)), 0.f);
        }
        idx += 4;
    }
    for (; idx < e1; ++idx) {
        const float4 m = meta[idx];
        const unsigned int g = hb[(size_t)__float_as_int(m.x) * 64 + lane];
        acc.x += fmaxf(bflo(g) + fmaf(m.y, w0.x, fmaf(m.z, w1.x, bb.x)), 0.f);
        acc.y += fmaxf(bfhi(g) + fmaf(m.y, w0.y, fmaf(m.z, w1.y, bb.y)), 0.f);
    }
    vh[(size_t)node * 64 + lane] = f2bf(acc.x) | (f2bf(acc.y) << 16);
}

// ---------- MFMA GEMM: leakyrelu(bf16(v) @ (wh+wl) + bias) -------------------
// Writes bf16 hb (layers 0,1) or f32 out (final layer).
__global__ __launch_bounds__(256) void gemm_k(
    const unsigned int* __restrict__ vh,   // [N][128] bf16 (packed x2)
    const uint4* __restrict__ whf,         // this layer's [4][8][64] frags
    const uint4* __restrict__ wlf,
    const float* __restrict__ bias,        // [HID]
    float* __restrict__ out,               // [N, HID] f32 (final layer)
    unsigned short* __restrict__ hbo,      // [N, HID] bf16 (layers 0,1)
    const int last)
{
    const int tid = threadIdx.x;
    const int wave = tid >> 6;
    const int lane = tid & 63;
    const int rowbase = blockIdx.x * 64 + wave * 16;
    const int arow = rowbase + (lane & 15);
    const int arowc = arow < NNODES ? arow : NNODES - 1;
    const uint4* vh4 = (const uint4*)vh;

    short8 a[4];
#pragma unroll
    for (int kt = 0; kt < 4; ++kt) {
        uint4 t = vh4[(size_t)arowc * 16 + kt * 4 + (lane >> 4)];
        a[kt] = *(short8*)&t;
    }

    const int crow0 = rowbase + (lane >> 4) * 4;
    const int ncol = lane & 15;
#pragma unroll
    for (int nt = 0; nt < 8; ++nt) {
        const float bv = bias[nt * 16 + ncol];
        f32x4 acc = {bv, bv, bv, bv};
#pragma unroll
        for (int kt = 0; kt < 4; ++kt) {
            uint4 th = whf[(kt * 8 + nt) * 64 + lane];
            uint4 tl = wlf[(kt * 8 + nt) * 64 + lane];
            acc = __builtin_amdgcn_mfma_f32_16x16x32_bf16(a[kt], *(short8*)&th, acc, 0, 0, 0);
            acc = __builtin_amdgcn_mfma_f32_16x16x32_bf16(a[kt], *(short8*)&tl, acc, 0, 0, 0);
        }
#pragma unroll
        for (int r = 0; r < 4; ++r) {
            const int rr = crow0 + r;
            if (rr < NNODES) {
                float v = acc[r];
                v = v >= 0.f ? v : NEG * v;
                if (last) out[(size_t)rr * HID + nt * 16 + ncol] = v;
                else      hbo[(size_t)rr * HID + nt * 16 + ncol] = (unsigned short)f2bf(v);
            }
        }
    }
}

extern "C" void kernel_launch(void* const* d_in, const int* in_sizes, int n_in,
                              void* d_out, int out_size, void* d_ws, size_t ws_size,
                              hipStream_t stream) {
    const float* x  = (const float*)d_in[0];
    const int*   ei = (const int*)d_in[1];
    const float* ea = (const float*)d_in[2];
    const float* Wl = (const float*)d_in[3];
    const float* bl = (const float*)d_in[4];
    const float* W  = (const float*)d_in[5];
    const float* b  = (const float*)d_in[6];

    float* h = (float*)d_out;                              // final f32 output

    float4* meta = (float4*)d_ws;                          // [E] {src,a0,a1,_}
    unsigned int* vh = (unsigned int*)(meta + NEDGES);     // [N*64] bf16x2 GEMM input
    unsigned int* hb = vh + (size_t)NNODES * 64;           // [N*64] bf16x2 node feats
    uint4* whf = (uint4*)(hb + (size_t)NNODES * 64);       // [3][4][8][64]
    uint4* wlf = whf + NLAYERS * 4 * 8 * 64;
    int* off  = (int*)(wlf + NLAYERS * 4 * 8 * 64);        // [N+1] (doubles as histogram)
    int* cur  = off + NNODES + 1;
    int* part = cur + NNODES;
    int* bsum = part + NNODES;

    // CSR metadata + W fragments + bf16(x) — reused/one-shot.
    hipMemsetAsync(off, 0, (NNODES + 1) * sizeof(int), stream);
    hist_k<<<(NEDGES + 255) / 256, 256, 0, stream>>>(ei, off);
    scan1_k<<<SCAN_B, 1024, 0, stream>>>(off, part, bsum);
    scan2_k<<<SCAN_B, 1024, 0, stream>>>(part, bsum, off, cur);
    fill_k<<<(NEDGES + 255) / 256, 256, 0, stream>>>(ei, ea, cur, meta);
    wconv_k<<<24, 256, 0, stream>>>(W, whf, wlf);
    cvt_k<<<(NNODES * 64 + 255) / 256, 256, 0, stream>>>(x, hb);

    for (int l = 0; l < NLAYERS; ++l) {
        agg_k<<<(NNODES + 3) / 4, 256, 0, stream>>>(
            hb, meta, Wl + (size_t)l * 2 * HID, bl + (size_t)l * HID, off, vh);
        gemm_k<<<(NNODES + 63) / 64, 256, 0, stream>>>(
            vh, whf + (size_t)l * 4 * 8 * 64, wlf + (size_t)l * 4 * 8 * 64,
            b + (size_t)l * HID, h, (unsigned short*)hb, l == NLAYERS - 1);
    }
}